// Round 2
// baseline (793.310 us; speedup 1.0000x reference)
//
#include <hip/hip_runtime.h>
#include <cstdint>
#include <cstddef>

// PureCartesianTensorProduct: B=4096, C1=C2=COUT=64, LMAX=2, FEAT=832, 15 paths.
// out[z,c,m] = sum_p sum_ab W_p[c,a,b] * T_p,m[z,a,b].
// MFMA f32_32x32x16_f16: A = W[c][k=a*64+b] read directly from global (L2-hot),
// B = T built in registers: x2-side held in regs per chunk (a-invariant),
// x1-side scalar per (a, z) from LDS. No barriers inside the a-loop.

#define FEAT 832
#define ZT 64

typedef _Float16 half8 __attribute__((ext_vector_type(8)));
typedef _Float16 half4 __attribute__((ext_vector_type(4)));
typedef float floatx16 __attribute__((ext_vector_type(16)));

struct Chunk {
  int wbase;      // p * 64*4096, element offset into f16 weight
  int o1[3];      // absolute x1 feature offset for term t (at a=0)
  int o2[3];      // absolute x2 feature offset for term t (at b=0)
  float sg[3];    // +-1
  int d1, d2, nt; // a-stride (3^L1), b-stride (3^L2), #terms (<=3)
};

__global__ void cvt_w_kernel(const float* __restrict__ w, _Float16* __restrict__ o, int n4) {
  int i = blockIdx.x * 256 + threadIdx.x;
  if (i < n4) {
    const float4 v = ((const float4*)w)[i];
    half4 h = { (_Float16)v.x, (_Float16)v.y, (_Float16)v.z, (_Float16)v.w };
    ((half4*)o)[i] = h;
  }
}

// XB union buffer: X2 view [t][zz][b] stride 72; X1 view [t][a][zz] stride 68.
template<int NT>
__device__ __forceinline__ void run_chunk(
    const Chunk C, const int zbase, const int zl, const int hf,
    const int crow, const int tid,
    const float* __restrict__ x1, const float* __restrict__ x2,
    const _Float16* __restrict__ Wh, _Float16* __restrict__ XB,
    floatx16& acc)
{
  __syncthreads();  // previous chunk's a-loop (X1 view readers) done

  // stage x2 tile: XB[t][zz][b] = (f16) x2[zbase+zz, o2[t] + b*d2]
  #pragma unroll
  for (int t = 0; t < NT; ++t) {
    const size_t base2 = (size_t)zbase * FEAT + C.o2[t];
    for (int e = tid; e < 64 * 64; e += 256) {
      const int zz = e >> 6, b = e & 63;
      XB[(t * 64 + zz) * 72 + b] = (_Float16)x2[base2 + (size_t)zz * FEAT + b * C.d2];
    }
  }
  __syncthreads();

  // fill per-lane x2 registers (a-invariant B-side): k-slot j -> b = ks*16+hf*8+j
  half8 x2r[NT][4];
  #pragma unroll
  for (int t = 0; t < NT; ++t) {
    #pragma unroll
    for (int ks = 0; ks < 4; ++ks)
      x2r[t][ks] = *(const half8*)&XB[(t * 64 + zl) * 72 + ks * 16 + hf * 8];
  }
  __syncthreads();  // done reading X2 view; reuse XB for X1 view

  // stage x1 transposed: XB[t][a][zz] = (f16)(x1[zbase+zz, o1[t]+a*d1] * sg[t])
  #pragma unroll
  for (int t = 0; t < NT; ++t) {
    const float sgf = C.sg[t];
    const int o1 = C.o1[t];
    for (int e = tid; e < 64 * 64; e += 256) {
      const int a = e & 63, zz = e >> 6;  // consecutive tid -> consecutive a (coalesced read)
      XB[(t * 64 + a) * 68 + zz] =
          (_Float16)(x1[(size_t)(zbase + zz) * FEAT + o1 + a * C.d1] * sgf);
    }
  }
  __syncthreads();

  const _Float16* __restrict__ Wp = Wh + C.wbase + (size_t)crow * 4096 + hf * 8;
  const _Float16* __restrict__ Xp = XB + zl;

  for (int a = 0; a < 64; ++a) {
    half8 af[4];
    #pragma unroll
    for (int ks = 0; ks < 4; ++ks)
      af[ks] = *(const half8*)(Wp + a * 64 + ks * 16);

    half8 sv[NT];
    #pragma unroll
    for (int t = 0; t < NT; ++t) {
      const _Float16 h = Xp[(t * 64 + a) * 68];
      sv[t] = half8{h, h, h, h, h, h, h, h};
    }

    #pragma unroll
    for (int ks = 0; ks < 4; ++ks) {
      half8 tb = sv[0] * x2r[0][ks];
      if (NT > 1) tb += sv[1] * x2r[1][ks];
      if (NT > 2) tb += sv[2] * x2r[2][ks];
      acc = __builtin_amdgcn_mfma_f32_32x32x16_f16(af[ks], tb, acc, 0, 0, 0);
    }
  }
}

__global__ __launch_bounds__(256, 4) void tp_kernel(
    const float* __restrict__ x1, const float* __restrict__ x2,
    const _Float16* __restrict__ Wh, float* __restrict__ out)
{
  __shared__ __align__(16) _Float16 XB[3 * 64 * 72]; // 27648 B union (X2/X1 views)
  __shared__ Chunk chs[7];
  __shared__ int nch_s;

  const int tid  = threadIdx.x;
  const int slot = blockIdx.y;           // 0: L0; 1..3: L1 m; 4..12: L2 (u,v)
  const int zbase = blockIdx.x * ZT;
  const int wv   = tid >> 6;
  const int lane = tid & 63;
  const int ln31 = lane & 31;
  const int hf   = lane >> 5;
  const int zgrp = wv & 1;               // z-group within tile
  const int cgrp = wv >> 1;              // c-group
  const int zl   = zgrp * 32 + ln31;     // z within tile (B-frag n = lane&31)
  const int zg   = zbase + zl;
  const int crow = cgrp * 32 + ln31;     // W row (A-frag m = lane&31)

  int offO, dO, mO;
  if (slot == 0)      { offO = 0;   dO = 1; mO = 0; }
  else if (slot < 4)  { offO = 64;  dO = 3; mO = slot - 1; }
  else                { offO = 256; dO = 9; mO = slot - 4; }

  if (tid == 0) {
    int n = 0;
    auto add = [&](int p, int L1, int L2,
                   int i0, int i1, int i2, int j0, int j1, int j2,
                   float s0, float s1, float s2, int nt) {
      const int offs[3] = {0, 64, 256};
      const int ds[3]   = {1, 3, 9};
      Chunk c;
      c.wbase = p * (64 * 4096);
      c.o1[0] = offs[L1] + i0; c.o1[1] = offs[L1] + i1; c.o1[2] = offs[L1] + i2;
      c.o2[0] = offs[L2] + j0; c.o2[1] = offs[L2] + j1; c.o2[2] = offs[L2] + j2;
      c.sg[0] = s0; c.sg[1] = s1; c.sg[2] = s2;
      c.d1 = ds[L1]; c.d2 = ds[L2]; c.nt = nt;
      chs[n++] = c;
    };
    if (slot == 0) {
      add(0, 0,0, 0,0,0, 0,0,0, 1,0,0, 1);                  // A0*B0
      add(5, 1,1, 0,1,2, 0,1,2, 1,1,1, 3);                  // sum_e A1[e]B1[e]
      add(13,2,2, 0,1,2, 0,1,2, 1,1,1, 3);                  // sum_g A2[g]B2[g] (3 chunks)
      add(13,2,2, 3,4,5, 3,4,5, 1,1,1, 3);
      add(13,2,2, 6,7,8, 6,7,8, 1,1,1, 3);
    } else if (slot < 4) {
      const int m = slot - 1, p1 = (m+1)%3, p2 = (m+2)%3;
      add(1, 0,1, 0,0,0, m,0,0, 1,0,0, 1);                  // A0*B1[m]
      add(3, 1,0, m,0,0, 0,0,0, 1,0,0, 1);                  // A1[m]*B0
      add(6, 1,1, p1,p2,0, p2,p1,0, 1,-1,0, 2);             // eps(m,x,y)A1[x]B1[y]
      add(7, 1,2, 0,1,2, 3*m,3*m+1,3*m+2, 1,1,1, 3);        // sum_e A1[e]B2[m,e]
      add(10,2,1, 3*m,3*m+1,3*m+2, 0,1,2, 1,1,1, 3);        // sum_e A2[m,e]B1[e]
      add(14,2,2, 3*p1,3*p1+1,3*p1+2, 3*p2,3*p2+1,3*p2+2, 1,1,1, 3);    // +A2[p1,e]B2[p2,e]
      add(14,2,2, 3*p2,3*p2+1,3*p2+2, 3*p1,3*p1+1,3*p1+2, -1,-1,-1, 3); // -A2[p2,e]B2[p1,e]
    } else {
      const int m = slot - 4, u = m/3, v = m%3, q1 = (v+1)%3, q2 = (v+2)%3;
      add(2, 0,2, 0,0,0, m,0,0, 1,0,0, 1);                  // A0*B2[u,v]
      add(4, 1,1, u,0,0, v,0,0, 1,0,0, 1);                  // A1[u]*B1[v]
      add(8, 1,2, q1,q2,0, 3*u+q2,3*u+q1,0, 1,-1,0, 2);     // eps(v,x,y)A1[x]B2[u,y]
      add(9, 2,0, m,0,0, 0,0,0, 1,0,0, 1);                  // A2[u,v]*B0
      add(11,2,1, 3*u+q1,3*u+q2,0, q2,q1,0, 1,-1,0, 2);     // eps(v,e,f)A2[u,e]B1[f]
      add(12,2,2, 3*u,3*u+1,3*u+2, 3*v,3*v+1,3*v+2, 1,1,1, 3); // sum_e A2[u,e]B2[v,e]
    }
    nch_s = n;
  }
  __syncthreads();
  const int nch = nch_s;

  floatx16 acc;
  #pragma unroll
  for (int r = 0; r < 16; ++r) acc[r] = 0.0f;

  for (int ci = 0; ci < nch; ++ci) {
    const Chunk C = chs[ci];  // block-uniform
    if (C.nt == 1)      run_chunk<1>(C, zbase, zl, hf, crow, tid, x1, x2, Wh, XB, acc);
    else if (C.nt == 2) run_chunk<2>(C, zbase, zl, hf, crow, tid, x1, x2, Wh, XB, acc);
    else                run_chunk<3>(C, zbase, zl, hf, crow, tid, x1, x2, Wh, XB, acc);
  }

  // epilogue: C/D 32x32 layout: col(z)=lane&31, row(c)=(r&3)+8*(r>>2)+4*(lane>>5)
  float* __restrict__ op = out + (size_t)zg * FEAT + offO + mO;
  #pragma unroll
  for (int r = 0; r < 16; ++r) {
    const int cr = (r & 3) + 8 * (r >> 2) + 4 * hf + cgrp * 32;
    op[(size_t)cr * dO] = acc[r];
  }
}

extern "C" void kernel_launch(void* const* d_in, const int* in_sizes, int n_in,
                              void* d_out, int out_size, void* d_ws, size_t ws_size,
                              hipStream_t stream) {
  const float* x1 = (const float*)d_in[0];
  const float* x2 = (const float*)d_in[1];
  const float* w  = (const float*)d_in[2];
  float* out = (float*)d_out;
  _Float16* Wh = (_Float16*)d_ws;            // 15*64*4096 f16 = 7.86 MB scratch

  const int nw = 15 * 64 * 4096;
  const int n4 = nw / 4;
  hipLaunchKernelGGL(cvt_w_kernel, dim3((n4 + 255) / 256), dim3(256), 0, stream, w, Wh, n4);

  dim3 grid(64, 13);  // 64 z-tiles x 13 output slots
  hipLaunchKernelGGL(tp_kernel, grid, dim3(256), 0, stream, x1, x2, Wh, out);
}

// Round 3
// 434.348 us; speedup vs baseline: 1.8264x; 1.8264x over previous
//
#include <hip/hip_runtime.h>
#include <cstdint>
#include <cstddef>

// PureCartesianTensorProduct: B=4096, C1=C2=COUT=64, LMAX=2, FEAT=832, 15 paths.
// out[z,c,m] = sum_p sum_ab W_p[c,a,b] * T_p,m[z,a,b].
// MFMA f32_32x32x16_f16, A = W pre-swizzled into A-frag order (coalesced global,
// L1/L2-hot), B = T built in registers: x2-side a-invariant regs, x1-side scalar
// per (a,z) from LDS. No barriers inside the a-loop.

#define FEAT 832
#define ZT 64

typedef _Float16 half8 __attribute__((ext_vector_type(8)));
typedef float floatx16 __attribute__((ext_vector_type(16)));

struct Chunk {
  int wbase;      // p * 262144, element offset into swizzled f16 weight
  int o1[3];      // absolute x1 feature offset for term t (at a=0)
  int o2[3];      // absolute x2 feature offset for term t (at b=0)
  float sg[3];    // +-1
  int d1, d2, nt; // a-stride (3^L1), b-stride (3^L2), #terms (<=3)
};

// Swizzle W f32 [p][c][k] -> f16 A-frag order:
// Wsw[((p*256 + ksg)*2 + cgrp)*512 + lane*8 + j] = W_p[cgrp*32+(lane&31)][ksg*16+(lane>>5)*8+j]
__global__ void swz_w_kernel(const float* __restrict__ w, _Float16* __restrict__ o) {
  const int i = blockIdx.x * 256 + threadIdx.x;     // one half8 chunk per thread
  const int lane = i & 63;
  const int pkc  = i >> 6;
  const int cgrp = pkc & 1;
  const int ksg  = (pkc >> 1) & 255;
  const int p    = pkc >> 9;
  const int c  = cgrp * 32 + (lane & 31);
  const int k0 = ksg * 16 + (lane >> 5) * 8;
  const float* src = w + (size_t)p * 262144 + (size_t)c * 4096 + k0;
  const float4 v0 = *(const float4*)(src);
  const float4 v1 = *(const float4*)(src + 4);
  half8 h = { (_Float16)v0.x, (_Float16)v0.y, (_Float16)v0.z, (_Float16)v0.w,
              (_Float16)v1.x, (_Float16)v1.y, (_Float16)v1.z, (_Float16)v1.w };
  *(half8*)(o + (size_t)i * 8) = h;
}

// XB union buffer: X2 view [t][zz] stride 72 (16B-aligned rows); X1 view [t][a] stride 66.
template<int NT>
__device__ __forceinline__ void run_chunk(
    const Chunk C, const int zbase, const int zl, const int hf, const int lane,
    const int cgrp, const int tid,
    const float* __restrict__ x1, const float* __restrict__ x2,
    const _Float16* __restrict__ Wh, _Float16* __restrict__ XB,
    floatx16& acc)
{
  __syncthreads();  // previous chunk's a-loop (X1 view readers) done

  // stage x2 tile: XB[t][zz][b] = (f16) x2[zbase+zz, o2[t] + b*d2]
  #pragma unroll
  for (int t = 0; t < NT; ++t) {
    const size_t base2 = (size_t)zbase * FEAT + C.o2[t];
    for (int e = tid; e < 64 * 64; e += 256) {
      const int zz = e >> 6, b = e & 63;
      XB[(t * 64 + zz) * 72 + b] = (_Float16)x2[base2 + (size_t)zz * FEAT + b * C.d2];
    }
  }
  __syncthreads();

  // fill per-lane x2 registers (a-invariant B-side): k-slot j -> b = ks*16+hf*8+j
  half8 x2r[NT][4];
  #pragma unroll
  for (int t = 0; t < NT; ++t) {
    #pragma unroll
    for (int ks = 0; ks < 4; ++ks)
      x2r[t][ks] = *(const half8*)&XB[(t * 64 + zl) * 72 + ks * 16 + hf * 8];
  }
  __syncthreads();  // done reading X2 view; reuse XB for X1 view

  // stage x1 transposed: XB[t][a][zz] = (f16)(x1[zbase+zz, o1[t]+a*d1] * sg[t])
  // stride 66 f16 -> consecutive a lands on consecutive banks (conflict-free)
  #pragma unroll
  for (int t = 0; t < NT; ++t) {
    const float sgf = C.sg[t];
    const int o1 = C.o1[t];
    for (int e = tid; e < 64 * 64; e += 256) {
      const int a = e & 63, zz = e >> 6;  // consecutive tid -> consecutive a
      XB[(t * 64 + a) * 66 + zz] =
          (_Float16)(x1[(size_t)(zbase + zz) * FEAT + o1 + a * C.d1] * sgf);
    }
  }
  __syncthreads();

  // swizzled W stream: per (a, ks) one coalesced 1KB wave-load
  const _Float16* __restrict__ Wp = Wh + C.wbase + cgrp * 512 + lane * 8;
  const _Float16* __restrict__ Xp = XB + zl;

  half8 af[4];
  #pragma unroll
  for (int ks = 0; ks < 4; ++ks)
    af[ks] = *(const half8*)(Wp + ks * 1024);

  for (int a = 0; a < 64; ++a) {
    half8 sv[NT];
    #pragma unroll
    for (int t = 0; t < NT; ++t) {
      const _Float16 h = Xp[(t * 64 + a) * 66];
      sv[t] = half8{h, h, h, h, h, h, h, h};
    }

    half8 afn[4];
    if (a < 63) {
      #pragma unroll
      for (int ks = 0; ks < 4; ++ks)
        afn[ks] = *(const half8*)(Wp + (a + 1) * 4096 + ks * 1024);
    }

    #pragma unroll
    for (int ks = 0; ks < 4; ++ks) {
      half8 tb = sv[0] * x2r[0][ks];
      if (NT > 1) tb += sv[1] * x2r[1][ks];
      if (NT > 2) tb += sv[2] * x2r[2][ks];
      acc = __builtin_amdgcn_mfma_f32_32x32x16_f16(af[ks], tb, acc, 0, 0, 0);
    }

    #pragma unroll
    for (int ks = 0; ks < 4; ++ks) af[ks] = afn[ks];
  }
}

__global__ __launch_bounds__(256, 3) void tp_kernel(
    const float* __restrict__ x1, const float* __restrict__ x2,
    const _Float16* __restrict__ Wh, float* __restrict__ out)
{
  __shared__ __align__(16) _Float16 XB[3 * 64 * 72]; // 27648 B union (X2/X1 views)
  __shared__ Chunk chs[7];
  __shared__ int nch_s;

  const int tid  = threadIdx.x;
  const int slot = blockIdx.y;           // 0: L0; 1..3: L1 m; 4..12: L2 (u,v)
  const int zbase = blockIdx.x * ZT;
  const int wv   = tid >> 6;
  const int lane = tid & 63;
  const int ln31 = lane & 31;
  const int hf   = lane >> 5;
  const int zgrp = wv & 1;               // z-group within tile
  const int cgrp = wv >> 1;              // c-group
  const int zl   = zgrp * 32 + ln31;     // z within tile (B-frag n = lane&31)
  const int zg   = zbase + zl;

  int offO, dO, mO;
  if (slot == 0)      { offO = 0;   dO = 1; mO = 0; }
  else if (slot < 4)  { offO = 64;  dO = 3; mO = slot - 1; }
  else                { offO = 256; dO = 9; mO = slot - 4; }

  if (tid == 0) {
    int n = 0;
    auto add = [&](int p, int L1, int L2,
                   int i0, int i1, int i2, int j0, int j1, int j2,
                   float s0, float s1, float s2, int nt) {
      const int offs[3] = {0, 64, 256};
      const int ds[3]   = {1, 3, 9};
      Chunk c;
      c.wbase = p * 262144;
      c.o1[0] = offs[L1] + i0; c.o1[1] = offs[L1] + i1; c.o1[2] = offs[L1] + i2;
      c.o2[0] = offs[L2] + j0; c.o2[1] = offs[L2] + j1; c.o2[2] = offs[L2] + j2;
      c.sg[0] = s0; c.sg[1] = s1; c.sg[2] = s2;
      c.d1 = ds[L1]; c.d2 = ds[L2]; c.nt = nt;
      chs[n++] = c;
    };
    if (slot == 0) {
      add(0, 0,0, 0,0,0, 0,0,0, 1,0,0, 1);                  // A0*B0
      add(5, 1,1, 0,1,2, 0,1,2, 1,1,1, 3);                  // sum_e A1[e]B1[e]
      add(13,2,2, 0,1,2, 0,1,2, 1,1,1, 3);                  // sum_g A2[g]B2[g] (3 chunks)
      add(13,2,2, 3,4,5, 3,4,5, 1,1,1, 3);
      add(13,2,2, 6,7,8, 6,7,8, 1,1,1, 3);
    } else if (slot < 4) {
      const int m = slot - 1, p1 = (m+1)%3, p2 = (m+2)%3;
      add(1, 0,1, 0,0,0, m,0,0, 1,0,0, 1);                  // A0*B1[m]
      add(3, 1,0, m,0,0, 0,0,0, 1,0,0, 1);                  // A1[m]*B0
      add(6, 1,1, p1,p2,0, p2,p1,0, 1,-1,0, 2);             // eps(m,x,y)A1[x]B1[y]
      add(7, 1,2, 0,1,2, 3*m,3*m+1,3*m+2, 1,1,1, 3);        // sum_e A1[e]B2[m,e]
      add(10,2,1, 3*m,3*m+1,3*m+2, 0,1,2, 1,1,1, 3);        // sum_e A2[m,e]B1[e]
      add(14,2,2, 3*p1,3*p1+1,3*p1+2, 3*p2,3*p2+1,3*p2+2, 1,1,1, 3);    // +A2[p1,e]B2[p2,e]
      add(14,2,2, 3*p2,3*p2+1,3*p2+2, 3*p1,3*p1+1,3*p1+2, -1,-1,-1, 3); // -A2[p2,e]B2[p1,e]
    } else {
      const int m = slot - 4, u = m/3, v = m%3, q1 = (v+1)%3, q2 = (v+2)%3;
      add(2, 0,2, 0,0,0, m,0,0, 1,0,0, 1);                  // A0*B2[u,v]
      add(4, 1,1, u,0,0, v,0,0, 1,0,0, 1);                  // A1[u]*B1[v]
      add(8, 1,2, q1,q2,0, 3*u+q2,3*u+q1,0, 1,-1,0, 2);     // eps(v,x,y)A1[x]B2[u,y]
      add(9, 2,0, m,0,0, 0,0,0, 1,0,0, 1);                  // A2[u,v]*B0
      add(11,2,1, 3*u+q1,3*u+q2,0, q2,q1,0, 1,-1,0, 2);     // eps(v,e,f)A2[u,e]B1[f]
      add(12,2,2, 3*u,3*u+1,3*u+2, 3*v,3*v+1,3*v+2, 1,1,1, 3); // sum_e A2[u,e]B2[v,e]
    }
    nch_s = n;
  }
  __syncthreads();
  const int nch = nch_s;

  floatx16 acc;
  #pragma unroll
  for (int r = 0; r < 16; ++r) acc[r] = 0.0f;

  for (int ci = 0; ci < nch; ++ci) {
    const Chunk C = chs[ci];  // block-uniform
    if (C.nt == 1)      run_chunk<1>(C, zbase, zl, hf, lane, cgrp, tid, x1, x2, Wh, XB, acc);
    else if (C.nt == 2) run_chunk<2>(C, zbase, zl, hf, lane, cgrp, tid, x1, x2, Wh, XB, acc);
    else                run_chunk<3>(C, zbase, zl, hf, lane, cgrp, tid, x1, x2, Wh, XB, acc);
  }

  // epilogue: C/D 32x32 layout: col(z)=lane&31, row(c)=(r&3)+8*(r>>2)+4*(lane>>5)
  float* __restrict__ op = out + (size_t)zg * FEAT + offO + mO;
  #pragma unroll
  for (int r = 0; r < 16; ++r) {
    const int cr = (r & 3) + 8 * (r >> 2) + 4 * hf + cgrp * 32;
    op[(size_t)cr * dO] = acc[r];
  }
}

extern "C" void kernel_launch(void* const* d_in, const int* in_sizes, int n_in,
                              void* d_out, int out_size, void* d_ws, size_t ws_size,
                              hipStream_t stream) {
  const float* x1 = (const float*)d_in[0];
  const float* x2 = (const float*)d_in[1];
  const float* w  = (const float*)d_in[2];
  float* out = (float*)d_out;
  _Float16* Wh = (_Float16*)d_ws;            // 15*64*4096 f16 = 7.86 MB scratch (swizzled)

  const int nchunks = 15 * 64 * 4096 / 8;    // 491520 half8 chunks
  hipLaunchKernelGGL(swz_w_kernel, dim3(nchunks / 256), dim3(256), 0, stream, w, Wh);

  dim3 grid(64, 13);  // 64 z-tiles x 13 output slots
  hipLaunchKernelGGL(tp_kernel, grid, dim3(256), 0, stream, x1, x2, Wh, out);
}